// Round 1
// baseline (1190.813 us; speedup 1.0000x reference)
//
#include <hip/hip_runtime.h>
#include <hip/hip_bf16.h>
#include <stdint.h>

#define GD 128
#define H1 128
#define H2 128
#define NBASES 32
#define NREL 8
#define K1 (NREL*GD + GD)   // 1152 = [8 relations x 128 agg | 128 raw x]

static inline size_t align256(size_t x){ return (x + 255) & ~(size_t)255; }

__device__ __forceinline__ float bf2f(unsigned int u16){
  union { uint32_t u; float f; } c; c.u = (u16 & 0xffffu) << 16; return c.f;
}
__device__ __forceinline__ unsigned short f2bf(float f){
  union { float f; uint32_t u; } c; c.f = f;
  uint32_t u = c.u;
  u += 0x7fffu + ((u >> 16) & 1u);   // RTNE (finite inputs)
  return (unsigned short)(u >> 16);
}

__device__ __forceinline__ void atomic_add_bf16x2(uint32_t* addr, float a, float b){
  uint32_t old = *(volatile uint32_t*)addr, assumed;
  do {
    assumed = old;
    float lo = bf2f(assumed & 0xffffu);
    float hi = bf2f(assumed >> 16);
    uint32_t nv = (uint32_t)f2bf(lo + a) | ((uint32_t)f2bf(hi + b) << 16);
    old = atomicCAS(addr, assumed, nv);
  } while (old != assumed);
}

// ---- B1 = [W_r stacked (r*128+i rows) | root], W_r = comp[r,:] @ basis ----
__global__ void k_build_B1(const float* __restrict__ comp, const float* __restrict__ basis,
                           const float* __restrict__ root, float* __restrict__ B1){
  int idx = blockIdx.x*blockDim.x + threadIdx.x;
  if (idx >= K1*H1) return;
  int kk = idx / H1, o = idx % H1;
  float v;
  if (kk < NREL*GD){
    int r = kk / GD, i = kk % GD;
    float acc = 0.f;
    #pragma unroll
    for (int b = 0; b < NBASES; ++b)
      acc += comp[r*NBASES + b] * basis[((size_t)b*GD + i)*H1 + o];
    v = acc;
  } else {
    v = root[(size_t)(kk - NREL*GD)*H1 + o];
  }
  B1[idx] = v;
}

// ---- B2 = [Wk | Wq | Wv | Wskip] (128 x 512), Bb = concat biases (512) ----
__global__ void k_build_B2(const float* __restrict__ wk, const float* __restrict__ wq,
                           const float* __restrict__ wv, const float* __restrict__ wsk,
                           const float* __restrict__ bk, const float* __restrict__ bq,
                           const float* __restrict__ bv, const float* __restrict__ bs,
                           float* __restrict__ B2, float* __restrict__ Bb){
  int idx = blockIdx.x*blockDim.x + threadIdx.x;
  if (idx < H1*512){
    int k = idx / 512, c = idx % 512;
    const float* w = (c < 128) ? wk : (c < 256) ? wq : (c < 384) ? wv : wsk;
    B2[idx] = w[k*H2 + (c & 127)];
  }
  if (idx < 512){
    const float* b = (idx < 128) ? bk : (idx < 256) ? bq : (idx < 384) ? bv : bs;
    Bb[idx] = b[idx & 127];
  }
}

// ---- cast x into A_big columns [1024..1152) ----
__global__ void k_cast_x(const float* __restrict__ x, unsigned short* __restrict__ A, int n){
  int idx = blockIdx.x*blockDim.x + threadIdx.x;
  if (idx >= n*GD) return;
  int node = idx / GD, i = idx % GD;
  A[(size_t)node*K1 + NREL*GD + i] = f2bf(x[idx]);
}

// ---- per-(relation,dst) edge counts ----
__global__ void k_cnt(const int* __restrict__ typ, const int* __restrict__ dst,
                      float* __restrict__ cnt, int E, int n){
  int e = blockIdx.x*blockDim.x + threadIdx.x;
  if (e >= E) return;
  atomicAdd(&cnt[(size_t)typ[e]*n + dst[e]], 1.0f);
}

// ---- scatter x[src]/cnt into A_big[dst, r*128 + i] (bf16 pk CAS). one wave/edge ----
__global__ void k_edge1(const int* __restrict__ src, const int* __restrict__ dst,
                        const int* __restrict__ typ, const float* __restrict__ x,
                        const float* __restrict__ cnt, uint32_t* __restrict__ A32,
                        int E, int n){
  int gid = blockIdx.x*blockDim.x + threadIdx.x;
  int wave = gid >> 6, lane = gid & 63;
  if (wave >= E) return;
  int s = src[wave], d = dst[wave], r = typ[wave];
  float w = 1.0f / cnt[(size_t)r*n + d];
  float2 xv = reinterpret_cast<const float2*>(x + (size_t)s*GD)[lane];
  atomic_add_bf16x2(A32 + (size_t)d*(K1/2) + r*(GD/2) + lane, xv.x*w, xv.y*w);
}

// ---- GEMM1: h[Npad,128] = A_big(bf16)[Npad,1152] @ B1(f32)[1152,128] + bias1 ----
__launch_bounds__(256)
__global__ void k_gemm1(const unsigned short* __restrict__ A, const float* __restrict__ B,
                        const float* __restrict__ bias, float* __restrict__ C){
  __shared__ float As[16][68];
  __shared__ float Bs[16][128];
  int t = threadIdx.x;
  int row0 = blockIdx.x * 64;
  int ty = t >> 4, tx = t & 15;
  int lr = t & 63, lk = (t >> 6) << 2;
  int bkr = t >> 5, bo = (t & 31) << 2;
  float acc[4][8];
  #pragma unroll
  for (int i = 0; i < 4; ++i)
    #pragma unroll
    for (int j = 0; j < 8; ++j) acc[i][j] = 0.f;

  for (int kt = 0; kt < K1; kt += 16){
    ushort4 av = *reinterpret_cast<const ushort4*>(A + (size_t)(row0+lr)*K1 + kt + lk);
    As[lk+0][lr] = bf2f(av.x); As[lk+1][lr] = bf2f(av.y);
    As[lk+2][lr] = bf2f(av.z); As[lk+3][lr] = bf2f(av.w);
    float4 b0 = *reinterpret_cast<const float4*>(B + (size_t)(kt+bkr)*H1 + bo);
    float4 b1 = *reinterpret_cast<const float4*>(B + (size_t)(kt+bkr+8)*H1 + bo);
    *reinterpret_cast<float4*>(&Bs[bkr][bo]) = b0;
    *reinterpret_cast<float4*>(&Bs[bkr+8][bo]) = b1;
    __syncthreads();
    #pragma unroll
    for (int kk = 0; kk < 16; ++kk){
      float4 a4 = *reinterpret_cast<const float4*>(&As[kk][ty<<2]);
      float4 b4a = *reinterpret_cast<const float4*>(&Bs[kk][tx<<3]);
      float4 b4b = *reinterpret_cast<const float4*>(&Bs[kk][(tx<<3)+4]);
      float a_[4] = {a4.x, a4.y, a4.z, a4.w};
      float b_[8] = {b4a.x, b4a.y, b4a.z, b4a.w, b4b.x, b4b.y, b4b.z, b4b.w};
      #pragma unroll
      for (int i = 0; i < 4; ++i)
        #pragma unroll
        for (int j = 0; j < 8; ++j) acc[i][j] += a_[i]*b_[j];
    }
    __syncthreads();
  }
  #pragma unroll
  for (int i = 0; i < 4; ++i){
    int rr = row0 + (ty<<2) + i;
    #pragma unroll
    for (int j = 0; j < 8; ++j)
      C[(size_t)rr*H1 + (tx<<3) + j] = acc[i][j] + bias[(tx<<3)+j];
  }
}

// ---- GEMM2: [N,512] = h @ B2 + Bb. cols<384 -> kqv(bf16), cols>=384 -> d_out(f32) ----
__launch_bounds__(256)
__global__ void k_gemm2(const float* __restrict__ A, const float* __restrict__ B2,
                        const float* __restrict__ Bb, unsigned short* __restrict__ kqv,
                        float* __restrict__ out, int n){
  __shared__ float As[16][68];
  __shared__ float Bs[16][64];
  int t = threadIdx.x;
  int row0 = blockIdx.x * 64;
  int c0 = blockIdx.y * 64;
  int ty = t >> 4, tx = t & 15;
  int lr = t & 63, lk = (t >> 6) << 2;
  int bkr = t >> 4, bc = (t & 15) << 2;
  float acc[4][4];
  #pragma unroll
  for (int i = 0; i < 4; ++i)
    #pragma unroll
    for (int j = 0; j < 4; ++j) acc[i][j] = 0.f;

  for (int kt = 0; kt < H1; kt += 16){
    float4 av = *reinterpret_cast<const float4*>(A + (size_t)(row0+lr)*H1 + kt + lk);
    As[lk+0][lr] = av.x; As[lk+1][lr] = av.y; As[lk+2][lr] = av.z; As[lk+3][lr] = av.w;
    float4 bvv = *reinterpret_cast<const float4*>(B2 + (size_t)(kt+bkr)*512 + c0 + bc);
    *reinterpret_cast<float4*>(&Bs[bkr][bc]) = bvv;
    __syncthreads();
    #pragma unroll
    for (int kk = 0; kk < 16; ++kk){
      float4 a4 = *reinterpret_cast<const float4*>(&As[kk][ty<<2]);
      float4 b4 = *reinterpret_cast<const float4*>(&Bs[kk][tx<<2]);
      float a_[4] = {a4.x, a4.y, a4.z, a4.w};
      float b_[4] = {b4.x, b4.y, b4.z, b4.w};
      #pragma unroll
      for (int i = 0; i < 4; ++i)
        #pragma unroll
        for (int j = 0; j < 4; ++j) acc[i][j] += a_[i]*b_[j];
    }
    __syncthreads();
  }
  #pragma unroll
  for (int i = 0; i < 4; ++i){
    int nn = row0 + (ty<<2) + i;
    if (nn >= n) continue;
    #pragma unroll
    for (int j = 0; j < 4; ++j){
      int c = c0 + (tx<<2) + j;
      float v = acc[i][j] + Bb[c];
      if (c < 384) kqv[(size_t)nn*384 + c] = f2bf(v);
      else         out[(size_t)nn*H2 + (c - 384)] = v;
    }
  }
}

// ---- out[d] += sigmoid(k[d]+q[s]) * v[s]. one wave/edge, bf16 kqv reads ----
__global__ void k_edge2(const int* __restrict__ src, const int* __restrict__ dst,
                        const uint32_t* __restrict__ kqv, float* __restrict__ out, int E){
  int gid = blockIdx.x*blockDim.x + threadIdx.x;
  int wave = gid >> 6, lane = gid & 63;
  if (wave >= E) return;
  int s = src[wave], d = dst[wave];
  uint32_t ku = kqv[(size_t)d*192 + lane];
  uint32_t qu = kqv[(size_t)s*192 + 64 + lane];
  uint32_t vu = kqv[(size_t)s*192 + 128 + lane];
  float k0 = bf2f(ku), k1 = bf2f(ku >> 16);
  float q0 = bf2f(qu), q1 = bf2f(qu >> 16);
  float v0 = bf2f(vu), v1 = bf2f(vu >> 16);
  float g0 = 1.f/(1.f + __expf(-(k0 + q0)));
  float g1 = 1.f/(1.f + __expf(-(k1 + q1)));
  atomicAdd(out + (size_t)d*H2 + 2*lane,     g0*v0);
  atomicAdd(out + (size_t)d*H2 + 2*lane + 1, g1*v1);
}

extern "C" void kernel_launch(void* const* d_in, const int* in_sizes, int n_in,
                              void* d_out, int out_size, void* d_ws, size_t ws_size,
                              hipStream_t stream){
  const float* x     = (const float*)d_in[0];
  const int*   eidx  = (const int*)  d_in[1];
  const int*   etype = (const int*)  d_in[3];
  const float* basis = (const float*)d_in[4];
  const float* comp  = (const float*)d_in[5];
  const float* root  = (const float*)d_in[6];
  const float* bias1 = (const float*)d_in[7];
  const float* wk    = (const float*)d_in[8];
  const float* bk    = (const float*)d_in[9];
  const float* wq    = (const float*)d_in[10];
  const float* bq    = (const float*)d_in[11];
  const float* wv    = (const float*)d_in[12];
  const float* bv    = (const float*)d_in[13];
  const float* wsk   = (const float*)d_in[14];
  const float* bs    = (const float*)d_in[15];
  const int n = in_sizes[0] / GD;        // 50000
  const int E = in_sizes[3];             // 600000
  const int npad = (n + 63) & ~63;       // 50048
  const int* esrc = eidx;
  const int* edst = eidx + E;
  float* out = (float*)d_out;

  char* w = (char*)d_ws;
  size_t off = 0;
  float* cnt = (float*)(w + off);            off = align256(off + (size_t)NREL*n*4);
  unsigned short* Abig = (unsigned short*)(w + off);
  size_t abytes = (size_t)npad*K1*2;         off = align256(off + abytes);
  float* B1 = (float*)(w + off);             off = align256(off + (size_t)K1*H1*4);
  float* B2 = (float*)(w + off);             off = align256(off + (size_t)H1*512*4);
  float* Bb = (float*)(w + off);             off = align256(off + 512*4);
  float* h  = (float*)(w + off);             off = align256(off + (size_t)npad*H1*4);
  unsigned short* kqv = (unsigned short*)(w + off); off = align256(off + (size_t)n*384*2);

  hipMemsetAsync(cnt, 0, (size_t)NREL*n*4, stream);
  hipMemsetAsync(Abig, 0, abytes, stream);

  k_build_B1<<<(K1*H1 + 255)/256, 256, 0, stream>>>(comp, basis, root, B1);
  k_build_B2<<<(H1*512 + 255)/256, 256, 0, stream>>>(wk, wq, wv, wsk, bk, bq, bv, bs, B2, Bb);
  k_cast_x<<<(n*GD + 255)/256, 256, 0, stream>>>(x, Abig, n);
  k_cnt<<<(E + 255)/256, 256, 0, stream>>>(etype, edst, cnt, E, n);
  k_edge1<<<((size_t)E*64 + 255)/256, 256, 0, stream>>>(esrc, edst, etype, x, cnt,
                                                        (uint32_t*)Abig, E, n);
  k_gemm1<<<npad/64, 256, 0, stream>>>(Abig, B1, bias1, h);
  k_gemm2<<<dim3(npad/64, 8), 256, 0, stream>>>(h, B2, Bb, kqv, out, n);
  k_edge2<<<((size_t)E*64 + 255)/256, 256, 0, stream>>>(esrc, edst, (const uint32_t*)kqv,
                                                        out, E);
}

// Round 2
// 686.494 us; speedup vs baseline: 1.7346x; 1.7346x over previous
//
#include <hip/hip_runtime.h>
#include <stdint.h>

#define GD 128
#define H1 128
#define H2 128
#define NBASES 32
#define NREL 8
#define K1 (NREL*GD + GD)   // 1152

typedef __attribute__((ext_vector_type(8))) short bf16x8;
typedef __attribute__((ext_vector_type(4))) float f32x4;

static inline size_t align256(size_t x){ return (x + 255) & ~(size_t)255; }

__device__ __forceinline__ float bf2f(uint32_t u16){
  union { uint32_t u; float f; } c; c.u = (u16 & 0xffffu) << 16; return c.f;
}
__device__ __forceinline__ unsigned short f2bf(float f){
  union { float f; uint32_t u; } c; c.f = f;
  uint32_t u = c.u;
  u += 0x7fffu + ((u >> 16) & 1u);   // RTNE (finite inputs)
  return (unsigned short)(u >> 16);
}

// ---- B1t[n][k] (bf16, [128][1152]): k<1024 -> W_r rows, else root ----
__global__ void k_build_B1t(const float* __restrict__ comp, const float* __restrict__ basis,
                            const float* __restrict__ root, unsigned short* __restrict__ B1t){
  int idx = blockIdx.x*blockDim.x + threadIdx.x;
  if (idx >= H1*K1) return;
  int nn = idx / K1, kk = idx % K1;
  float v;
  if (kk < NREL*GD){
    int r = kk >> 7, i = kk & 127;
    float acc = 0.f;
    #pragma unroll
    for (int b = 0; b < NBASES; ++b)
      acc += comp[r*NBASES + b] * basis[((size_t)b*GD + i)*H1 + nn];
    v = acc;
  } else {
    v = root[(size_t)(kk - NREL*GD)*H1 + nn];
  }
  B1t[idx] = f2bf(v);
}

// ---- B2t[c][k] (bf16, [512][128]) = [Wk|Wq|Wv|Wskip]^T ; Bb = biases (512 f32) ----
__global__ void k_build_B2t(const float* __restrict__ wk, const float* __restrict__ wq,
                            const float* __restrict__ wv, const float* __restrict__ wsk,
                            const float* __restrict__ bk, const float* __restrict__ bq,
                            const float* __restrict__ bv, const float* __restrict__ bs,
                            unsigned short* __restrict__ B2t, float* __restrict__ Bb){
  int idx = blockIdx.x*blockDim.x + threadIdx.x;
  if (idx < 512*H1){
    int c = idx / H1, k = idx % H1;
    const float* w = (c < 128) ? wk : (c < 256) ? wq : (c < 384) ? wv : wsk;
    B2t[idx] = f2bf(w[(size_t)k*H2 + (c & 127)]);
  }
  if (idx < 512){
    const float* b = (idx < 128) ? bk : (idx < 256) ? bq : (idx < 384) ? bv : bs;
    Bb[idx] = b[idx & 127];
  }
}

__global__ void k_cast_x(const float* __restrict__ x, unsigned short* __restrict__ xbf, int cnt){
  int idx = blockIdx.x*blockDim.x + threadIdx.x;
  if (idx < cnt) xbf[idx] = f2bf(x[idx]);
}

__global__ void k_hist(const int* __restrict__ dst, int* __restrict__ deg, int E){
  int e = blockIdx.x*blockDim.x + threadIdx.x;
  if (e < E) atomicAdd(&deg[dst[e]], 1);
}

// single-block exclusive scan over n (Hillis-Steele per 1024-chunk + carry)
__global__ void k_scan(const int* __restrict__ deg, int* __restrict__ off,
                       int* __restrict__ cursor, int n){
  __shared__ int buf[1024];
  __shared__ int carry;
  int t = threadIdx.x;
  if (t == 0) carry = 0;
  __syncthreads();
  for (int base = 0; base < n; base += 1024){
    int v = (base + t < n) ? deg[base + t] : 0;
    buf[t] = v; __syncthreads();
    #pragma unroll
    for (int s = 1; s < 1024; s <<= 1){
      int u = (t >= s) ? buf[t - s] : 0;
      __syncthreads();
      buf[t] += u;
      __syncthreads();
    }
    int inc = buf[t];
    int c = carry;
    if (base + t < n){ off[base+t] = c + inc - v; cursor[base+t] = c + inc - v; }
    __syncthreads();
    if (t == 1023) carry = c + buf[1023];
    __syncthreads();
  }
}

// pk[pos] = src | (typ<<20), dst-sorted via cursor
__global__ void k_scatter(const int* __restrict__ src, const int* __restrict__ dst,
                          const int* __restrict__ typ, int* __restrict__ cursor,
                          int* __restrict__ pk, int E){
  int e = blockIdx.x*blockDim.x + threadIdx.x;
  if (e >= E) return;
  int pos = atomicAdd(&cursor[dst[e]], 1);
  pk[pos] = src[e] | (typ[e] << 20);
}

// ---- one wave per dst node: per-relation mean of x[src] -> Abig row (bf16) ----
__global__ void k_edge1(const int* __restrict__ off, const int* __restrict__ deg,
                        const int* __restrict__ pk, const unsigned short* __restrict__ xbf,
                        unsigned short* __restrict__ Abig, int n, int npad){
  int wid = blockIdx.x*(blockDim.x >> 6) + (threadIdx.x >> 6);
  int lane = threadIdx.x & 63;
  if (wid >= npad) return;
  uint32_t* Arow = (uint32_t*)(Abig + (size_t)wid*K1);
  if (wid >= n){
    #pragma unroll
    for (int r = 0; r < 9; ++r) Arow[r*64 + lane] = 0u;
    return;
  }
  float a0[8], a1[8]; int cr[8];
  #pragma unroll
  for (int r = 0; r < 8; ++r){ a0[r] = 0.f; a1[r] = 0.f; cr[r] = 0; }
  int o = off[wid], dg = deg[wid];
  for (int j = 0; j < dg; ++j){
    int p = pk[o + j];
    int s = p & 0xFFFFF, r = p >> 20;
    uint32_t xv = ((const uint32_t*)xbf)[(size_t)s*64 + lane];
    float x0 = bf2f(xv), x1 = bf2f(xv >> 16);
    #pragma unroll
    for (int rr = 0; rr < 8; ++rr){
      bool m = (rr == r);
      a0[rr] += m ? x0 : 0.f;
      a1[rr] += m ? x1 : 0.f;
      cr[rr] += m ? 1 : 0;
    }
  }
  #pragma unroll
  for (int rr = 0; rr < 8; ++rr){
    float inv = 1.f / (float)(cr[rr] > 0 ? cr[rr] : 1);
    Arow[rr*64 + lane] = (uint32_t)f2bf(a0[rr]*inv) | ((uint32_t)f2bf(a1[rr]*inv) << 16);
  }
  Arow[512 + lane] = ((const uint32_t*)xbf)[(size_t)wid*64 + lane];
}

// ---- GEMM1: h(bf16)[npad,128] = Abig(bf16)[npad,1152] @ B1t^T + bias1 (MFMA) ----
__launch_bounds__(256)
__global__ void k_gemm1(const unsigned short* __restrict__ A, const unsigned short* __restrict__ Bt,
                        const float* __restrict__ bias, unsigned short* __restrict__ h){
  int wave = threadIdx.x >> 6, lane = threadIdx.x & 63;
  int row0 = blockIdx.x*64 + wave*16;
  int mrow = lane & 15, quad = lane >> 4;
  f32x4 acc[8];
  #pragma unroll
  for (int i = 0; i < 8; ++i) acc[i] = (f32x4){0.f,0.f,0.f,0.f};
  const unsigned short* Aq = A + (size_t)(row0 + mrow)*K1 + quad*8;
  const unsigned short* Bq = Bt + (size_t)mrow*K1 + quad*8;
  for (int kt = 0; kt < K1; kt += 32){
    bf16x8 af = *(const bf16x8*)(Aq + kt);
    #pragma unroll
    for (int nt = 0; nt < 8; ++nt){
      bf16x8 bf = *(const bf16x8*)(Bq + (size_t)nt*16*K1 + kt);
      acc[nt] = __builtin_amdgcn_mfma_f32_16x16x32_bf16(af, bf, acc[nt], 0, 0, 0);
    }
  }
  #pragma unroll
  for (int nt = 0; nt < 8; ++nt){
    int col = nt*16 + mrow;
    float bcol = bias[col];
    #pragma unroll
    for (int i = 0; i < 4; ++i){
      int rr = row0 + quad*4 + i;
      h[(size_t)rr*H1 + col] = f2bf(acc[nt][i] + bcol);
    }
  }
}

// ---- GEMM2: [npad,512] = h @ B2t^T + Bb; cols<384 -> kqv(bf16, qv pair-interleaved),
//      cols>=384 -> out (f32 skip) ----
__launch_bounds__(256)
__global__ void k_gemm2(const unsigned short* __restrict__ h, const unsigned short* __restrict__ B2t,
                        const float* __restrict__ Bb, unsigned short* __restrict__ kqv,
                        float* __restrict__ out, int n){
  int wave = threadIdx.x >> 6, lane = threadIdx.x & 63;
  int row0 = blockIdx.x*64 + wave*16;
  int c0 = blockIdx.y*256;
  int mrow = lane & 15, quad = lane >> 4;
  f32x4 acc[16];
  #pragma unroll
  for (int i = 0; i < 16; ++i) acc[i] = (f32x4){0.f,0.f,0.f,0.f};
  const unsigned short* Aq = h + (size_t)(row0 + mrow)*H1 + quad*8;
  const unsigned short* Bq = B2t + (size_t)(c0 + mrow)*H1 + quad*8;
  #pragma unroll
  for (int kt = 0; kt < H1; kt += 32){
    bf16x8 af = *(const bf16x8*)(Aq + kt);
    #pragma unroll
    for (int nt = 0; nt < 16; ++nt){
      bf16x8 bf = *(const bf16x8*)(Bq + (size_t)nt*16*H1 + kt);
      acc[nt] = __builtin_amdgcn_mfma_f32_16x16x32_bf16(af, bf, acc[nt], 0, 0, 0);
    }
  }
  #pragma unroll
  for (int nt = 0; nt < 16; ++nt){
    int col = c0 + nt*16 + mrow;
    float bcol = Bb[col];
    #pragma unroll
    for (int i = 0; i < 4; ++i){
      int rr = row0 + quad*4 + i;
      if (rr >= n) continue;
      float v = acc[nt][i] + bcol;
      if (col < 128){
        kqv[(size_t)rr*384 + col] = f2bf(v);
      } else if (col < 256){
        int j = col - 128;
        kqv[(size_t)rr*384 + 128 + ((j >> 1) << 2) + (j & 1)] = f2bf(v);
      } else if (col < 384){
        int j = col - 256;
        kqv[(size_t)rr*384 + 128 + ((j >> 1) << 2) + 2 + (j & 1)] = f2bf(v);
      } else {
        out[(size_t)rr*H2 + (col - 384)] = v;
      }
    }
  }
}

// ---- one wave per dst node: out[d] += sum_e sigmoid(k[d]+q[s])*v[s] ----
__global__ void k_edge2(const int* __restrict__ off, const int* __restrict__ deg,
                        const int* __restrict__ pk, const unsigned short* __restrict__ kqv,
                        float* __restrict__ out, int n){
  int wid = blockIdx.x*(blockDim.x >> 6) + (threadIdx.x >> 6);
  int lane = threadIdx.x & 63;
  if (wid >= n) return;
  uint32_t ku = ((const uint32_t*)kqv)[(size_t)wid*192 + lane];
  float k0 = bf2f(ku), k1 = bf2f(ku >> 16);
  float a0 = 0.f, a1 = 0.f;
  int o = off[wid], dg = deg[wid];
  for (int j = 0; j < dg; ++j){
    int s = pk[o + j] & 0xFFFFF;
    uint2 qv = *(const uint2*)((const uint32_t*)kqv + (size_t)s*192 + 64 + lane*2);
    float q0 = bf2f(qv.x), q1 = bf2f(qv.x >> 16);
    float v0 = bf2f(qv.y), v1 = bf2f(qv.y >> 16);
    float g0 = 1.f / (1.f + __expf(-(k0 + q0)));
    float g1 = 1.f / (1.f + __expf(-(k1 + q1)));
    a0 += g0*v0; a1 += g1*v1;
  }
  float2* op = (float2*)(out + (size_t)wid*H2);
  float2 cur = op[lane];
  cur.x += a0; cur.y += a1;
  op[lane] = cur;
}

extern "C" void kernel_launch(void* const* d_in, const int* in_sizes, int n_in,
                              void* d_out, int out_size, void* d_ws, size_t ws_size,
                              hipStream_t stream){
  const float* x     = (const float*)d_in[0];
  const int*   eidx  = (const int*)  d_in[1];
  const int*   etype = (const int*)  d_in[3];
  const float* basis = (const float*)d_in[4];
  const float* comp  = (const float*)d_in[5];
  const float* root  = (const float*)d_in[6];
  const float* bias1 = (const float*)d_in[7];
  const float* wk    = (const float*)d_in[8];
  const float* bk    = (const float*)d_in[9];
  const float* wq    = (const float*)d_in[10];
  const float* bq    = (const float*)d_in[11];
  const float* wv    = (const float*)d_in[12];
  const float* bv    = (const float*)d_in[13];
  const float* wsk   = (const float*)d_in[14];
  const float* bs    = (const float*)d_in[15];
  const int n = in_sizes[0] / GD;        // 50000
  const int E = in_sizes[3];             // 600000
  const int npad = (n + 63) & ~63;       // 50048
  const int* esrc = eidx;
  const int* edst = eidx + E;
  float* out = (float*)d_out;

  char* w = (char*)d_ws;
  size_t off = 0;
  unsigned short* xbf  = (unsigned short*)(w + off); off = align256(off + (size_t)n*GD*2);
  unsigned short* Abig = (unsigned short*)(w + off); off = align256(off + (size_t)npad*K1*2);
  unsigned short* B1t  = (unsigned short*)(w + off); off = align256(off + (size_t)H1*K1*2);
  unsigned short* B2t  = (unsigned short*)(w + off); off = align256(off + (size_t)512*H1*2);
  float* Bb            = (float*)(w + off);          off = align256(off + 512*4);
  unsigned short* hbuf = (unsigned short*)(w + off); off = align256(off + (size_t)npad*H1*2);
  unsigned short* kqv  = (unsigned short*)(w + off); off = align256(off + (size_t)n*384*2);
  int* deg             = (int*)(w + off);            off = align256(off + (size_t)npad*4);
  int* offs            = (int*)(w + off);            off = align256(off + (size_t)npad*4);
  int* cursor          = (int*)(w + off);            off = align256(off + (size_t)npad*4);
  int* pk              = (int*)(w + off);            off = align256(off + (size_t)E*4);

  hipMemsetAsync(deg, 0, (size_t)npad*4, stream);

  k_build_B1t<<<(H1*K1 + 255)/256, 256, 0, stream>>>(comp, basis, root, B1t);
  k_build_B2t<<<(512*H1 + 255)/256, 256, 0, stream>>>(wk, wq, wv, wsk, bk, bq, bv, bs, B2t, Bb);
  k_cast_x<<<(n*GD + 255)/256, 256, 0, stream>>>(x, xbf, n*GD);
  k_hist<<<(E + 255)/256, 256, 0, stream>>>(edst, deg, E);
  k_scan<<<1, 1024, 0, stream>>>(deg, offs, cursor, n);
  k_scatter<<<(E + 255)/256, 256, 0, stream>>>(esrc, edst, etype, cursor, pk, E);
  k_edge1<<<(npad + 3)/4, 256, 0, stream>>>(offs, deg, pk, xbf, Abig, n, npad);
  k_gemm1<<<npad/64, 256, 0, stream>>>(Abig, B1t, bias1, hbuf);
  k_gemm2<<<dim3(npad/64, 2), 256, 0, stream>>>(hbuf, B2t, Bb, kqv, out, n);
  k_edge2<<<(n + 3)/4, 256, 0, stream>>>(offs, deg, pk, kqv, out, n);
}

// Round 3
// 495.544 us; speedup vs baseline: 2.4030x; 1.3853x over previous
//
#include <hip/hip_runtime.h>
#include <stdint.h>

#define GD 128
#define H1 128
#define H2 128
#define NBASES 32
#define NREL 8
#define K1 (NREL*GD + GD)   // 1152

typedef __attribute__((ext_vector_type(8))) short bf16x8;
typedef __attribute__((ext_vector_type(4))) float f32x4;

static inline size_t align256(size_t x){ return (x + 255) & ~(size_t)255; }

__device__ __forceinline__ float bf2f(uint32_t u16){
  union { uint32_t u; float f; } c; c.u = (u16 & 0xffffu) << 16; return c.f;
}
__device__ __forceinline__ unsigned short f2bf(float f){
  union { float f; uint32_t u; } c; c.f = f;
  uint32_t u = c.u;
  u += 0x7fffu + ((u >> 16) & 1u);   // RTNE (finite inputs)
  return (unsigned short)(u >> 16);
}

// async global->LDS, 16B per lane; lds dst = wave-uniform base + lane*16
__device__ __forceinline__ void async_copy16(void* lds_dst, const void* gsrc){
  __builtin_amdgcn_global_load_lds(
      (const __attribute__((address_space(1))) uint32_t*)gsrc,
      (__attribute__((address_space(3))) uint32_t*)lds_dst, 16, 0, 0);
}

// ---- B1t[n][k] (bf16, [128][1152]): k<1024 -> W_r rows, else root ----
__global__ void k_build_B1t(const float* __restrict__ comp, const float* __restrict__ basis,
                            const float* __restrict__ root, unsigned short* __restrict__ B1t){
  int idx = blockIdx.x*blockDim.x + threadIdx.x;
  if (idx >= H1*K1) return;
  int nn = idx / K1, kk = idx % K1;
  float v;
  if (kk < NREL*GD){
    int r = kk >> 7, i = kk & 127;
    float acc = 0.f;
    #pragma unroll
    for (int b = 0; b < NBASES; ++b)
      acc += comp[r*NBASES + b] * basis[((size_t)b*GD + i)*H1 + nn];
    v = acc;
  } else {
    v = root[(size_t)(kk - NREL*GD)*H1 + nn];
  }
  B1t[idx] = f2bf(v);
}

// ---- B2t[c][k] (bf16, [512][128]) = [Wk|Wq|Wv|Wskip]^T ; Bb = biases (512 f32) ----
__global__ void k_build_B2t(const float* __restrict__ wk, const float* __restrict__ wq,
                            const float* __restrict__ wv, const float* __restrict__ wsk,
                            const float* __restrict__ bk, const float* __restrict__ bq,
                            const float* __restrict__ bv, const float* __restrict__ bs,
                            unsigned short* __restrict__ B2t, float* __restrict__ Bb){
  int idx = blockIdx.x*blockDim.x + threadIdx.x;
  if (idx < 512*H1){
    int c = idx / H1, k = idx % H1;
    const float* w = (c < 128) ? wk : (c < 256) ? wq : (c < 384) ? wv : wsk;
    B2t[idx] = f2bf(w[(size_t)k*H2 + (c & 127)]);
  }
  if (idx < 512){
    const float* b = (idx < 128) ? bk : (idx < 256) ? bq : (idx < 384) ? bv : bs;
    Bb[idx] = b[idx & 127];
  }
}

__global__ void k_cast_x(const float* __restrict__ x, unsigned short* __restrict__ xbf, int cnt){
  int idx = blockIdx.x*blockDim.x + threadIdx.x;
  if (idx < cnt) xbf[idx] = f2bf(x[idx]);
}

__global__ void k_hist(const int* __restrict__ dst, int* __restrict__ deg, int E){
  int e = blockIdx.x*blockDim.x + threadIdx.x;
  if (e < E) atomicAdd(&deg[dst[e]], 1);
}

// single-block exclusive scan, shuffle-based (3-4 barriers per 1024-chunk)
__global__ void k_scan(const int* __restrict__ deg, int* __restrict__ off,
                       int* __restrict__ cursor, int n){
  __shared__ int wsum[16];
  __shared__ int carry;
  int t = threadIdx.x, lane = t & 63, w = t >> 6;
  if (t == 0) carry = 0;
  __syncthreads();
  for (int base = 0; base < n; base += 1024){
    int v = (base + t < n) ? deg[base + t] : 0;
    int x = v;
    #pragma unroll
    for (int s = 1; s < 64; s <<= 1){
      int u = __shfl_up(x, s, 64);
      if (lane >= s) x += u;
    }
    if (lane == 63) wsum[w] = x;
    __syncthreads();
    if (t < 16){
      int y = wsum[t];
      #pragma unroll
      for (int s = 1; s < 16; s <<= 1){
        int u = __shfl_up(y, s, 16);
        if (t >= s) y += u;
      }
      wsum[t] = y;
    }
    __syncthreads();
    int woff = (w > 0) ? wsum[w-1] : 0;
    int excl = carry + woff + x - v;
    if (base + t < n){ off[base+t] = excl; cursor[base+t] = excl; }
    int total = wsum[15];
    __syncthreads();
    if (t == 0) carry += total;
    __syncthreads();
  }
}

// pk[pos] = src | (typ<<20), dst-sorted via cursor
__global__ void k_scatter(const int* __restrict__ src, const int* __restrict__ dst,
                          const int* __restrict__ typ, int* __restrict__ cursor,
                          int* __restrict__ pk, int E){
  int e = blockIdx.x*blockDim.x + threadIdx.x;
  if (e >= E) return;
  int pos = atomicAdd(&cursor[dst[e]], 1);
  pk[pos] = src[e] | (typ[e] << 20);
}

// ---- one wave per dst node: per-relation mean of x[src] -> Abig row (bf16) ----
__global__ void k_edge1(const int* __restrict__ off, const int* __restrict__ deg,
                        const int* __restrict__ pk, const unsigned short* __restrict__ xbf,
                        unsigned short* __restrict__ Abig, int n, int npad){
  int wid = blockIdx.x*(blockDim.x >> 6) + (threadIdx.x >> 6);
  int lane = threadIdx.x & 63;
  if (wid >= npad) return;
  uint32_t* Arow = (uint32_t*)(Abig + (size_t)wid*K1);
  if (wid >= n){
    #pragma unroll
    for (int r = 0; r < 9; ++r) Arow[r*64 + lane] = 0u;
    return;
  }
  float a0[8], a1[8]; int cr[8];
  #pragma unroll
  for (int r = 0; r < 8; ++r){ a0[r] = 0.f; a1[r] = 0.f; cr[r] = 0; }
  int o = off[wid], dg = deg[wid];
  for (int j = 0; j < dg; ++j){
    int p = pk[o + j];
    int s = p & 0xFFFFF, r = p >> 20;
    uint32_t xv = ((const uint32_t*)xbf)[(size_t)s*64 + lane];
    float x0 = bf2f(xv), x1 = bf2f(xv >> 16);
    #pragma unroll
    for (int rr = 0; rr < 8; ++rr){
      bool m = (rr == r);
      a0[rr] += m ? x0 : 0.f;
      a1[rr] += m ? x1 : 0.f;
      cr[rr] += m ? 1 : 0;
    }
  }
  #pragma unroll
  for (int rr = 0; rr < 8; ++rr){
    float inv = 1.f / (float)(cr[rr] > 0 ? cr[rr] : 1);
    Arow[rr*64 + lane] = (uint32_t)f2bf(a0[rr]*inv) | ((uint32_t)f2bf(a1[rr]*inv) << 16);
  }
  Arow[512 + lane] = ((const uint32_t*)xbf)[(size_t)wid*64 + lane];
}

// =================== m97-style tiled MFMA GEMMs ===================
// Tile 128x128, 256 threads = 4 waves, each wave a 64x64 quadrant (4x4 MFMA 16x16x32).
// LDS: As 128 rows x 32 k (8KB) + Bs 128 cols x 32 k (8KB), single-buffered 2-barrier loop.
// k-block XOR swizzle: logical quad q of row r stored at physical q ^ ((r>>1)&3); staging
// stays lane-contiguous (global_load_lds constraint), readers get <=2-way aliasing (free).

// GEMM1: h(bf16)[npad,128] = Abig[npad,1152] @ B1t^T + bias1
__launch_bounds__(256)
__global__ void k_gemm1(const unsigned short* __restrict__ A, const unsigned short* __restrict__ Bt,
                        const float* __restrict__ bias, unsigned short* __restrict__ h){
  __shared__ char lds[16384];
  int t = threadIdx.x, lane = t & 63, wave = t >> 6;
  int row0 = blockIdx.x * 128;
  int mrow = lane & 15, quad = lane >> 4;
  int wrow = (wave & 1) * 64, wcol = (wave >> 1) * 64;
  int s = (mrow >> 1) & 3;

  const unsigned short* Asrc = A + (size_t)(row0 + (t >> 2))*K1 + (((t & 3) ^ ((t >> 3) & 3)) << 3);
  const unsigned short* Bsrc = Bt + (size_t)(t >> 2)*K1 + (((t & 3) ^ ((t >> 3) & 3)) << 3);
  char* ldsw = lds + wave*1024;

  int aoff = (wrow + mrow)*64 + ((quad ^ s) << 4);
  int boff = 8192 + (wcol + mrow)*64 + ((quad ^ s) << 4);

  f32x4 acc[4][4];
  #pragma unroll
  for (int i = 0; i < 4; ++i)
    #pragma unroll
    for (int j = 0; j < 4; ++j) acc[i][j] = (f32x4){0.f,0.f,0.f,0.f};

  for (int kt = 0; kt < K1; kt += 32){
    __syncthreads();
    async_copy16(ldsw,                 Asrc + kt);
    async_copy16(ldsw + 4096,          Asrc + (size_t)64*K1 + kt);
    async_copy16(ldsw + 8192,          Bsrc + kt);
    async_copy16(ldsw + 12288,         Bsrc + (size_t)64*K1 + kt);
    __syncthreads();
    bf16x8 af[4], bf[4];
    #pragma unroll
    for (int i = 0; i < 4; ++i) af[i] = *(const bf16x8*)(lds + aoff + i*1024);
    #pragma unroll
    for (int j = 0; j < 4; ++j) bf[j] = *(const bf16x8*)(lds + boff + j*1024);
    #pragma unroll
    for (int i = 0; i < 4; ++i)
      #pragma unroll
      for (int j = 0; j < 4; ++j)
        acc[i][j] = __builtin_amdgcn_mfma_f32_16x16x32_bf16(af[i], bf[j], acc[i][j], 0, 0, 0);
  }
  #pragma unroll
  for (int j = 0; j < 4; ++j){
    int col = wcol + j*16 + mrow;
    float bcol = bias[col];
    #pragma unroll
    for (int i = 0; i < 4; ++i)
      #pragma unroll
      for (int rg = 0; rg < 4; ++rg){
        int row = wrow + i*16 + quad*4 + rg;
        h[(size_t)(row0 + row)*H1 + col] = f2bf(acc[i][j][rg] + bcol);
      }
  }
}

// GEMM2: [npad,512] = h @ B2t^T + Bb; cols<384 -> kqv(bf16, qv pair-interleaved),
//        cols>=384 -> out (f32 skip)
__launch_bounds__(256)
__global__ void k_gemm2(const unsigned short* __restrict__ A, const unsigned short* __restrict__ Bt,
                        const float* __restrict__ Bb, unsigned short* __restrict__ kqv,
                        float* __restrict__ out, int n){
  __shared__ char lds[16384];
  int t = threadIdx.x, lane = t & 63, wave = t >> 6;
  int row0 = blockIdx.x * 128;
  int c0 = blockIdx.y * 128;
  int mrow = lane & 15, quad = lane >> 4;
  int wrow = (wave & 1) * 64, wcol = (wave >> 1) * 64;
  int s = (mrow >> 1) & 3;

  const unsigned short* Asrc = A + (size_t)(row0 + (t >> 2))*H1 + (((t & 3) ^ ((t >> 3) & 3)) << 3);
  const unsigned short* Bsrc = Bt + (size_t)(c0 + (t >> 2))*H1 + (((t & 3) ^ ((t >> 3) & 3)) << 3);
  char* ldsw = lds + wave*1024;

  int aoff = (wrow + mrow)*64 + ((quad ^ s) << 4);
  int boff = 8192 + (wcol + mrow)*64 + ((quad ^ s) << 4);

  f32x4 acc[4][4];
  #pragma unroll
  for (int i = 0; i < 4; ++i)
    #pragma unroll
    for (int j = 0; j < 4; ++j) acc[i][j] = (f32x4){0.f,0.f,0.f,0.f};

  #pragma unroll
  for (int kt = 0; kt < H1; kt += 32){
    __syncthreads();
    async_copy16(ldsw,         Asrc + kt);
    async_copy16(ldsw + 4096,  Asrc + (size_t)64*H1 + kt);
    async_copy16(ldsw + 8192,  Bsrc + kt);
    async_copy16(ldsw + 12288, Bsrc + (size_t)64*H1 + kt);
    __syncthreads();
    bf16x8 af[4], bf[4];
    #pragma unroll
    for (int i = 0; i < 4; ++i) af[i] = *(const bf16x8*)(lds + aoff + i*1024);
    #pragma unroll
    for (int j = 0; j < 4; ++j) bf[j] = *(const bf16x8*)(lds + boff + j*1024);
    #pragma unroll
    for (int i = 0; i < 4; ++i)
      #pragma unroll
      for (int j = 0; j < 4; ++j)
        acc[i][j] = __builtin_amdgcn_mfma_f32_16x16x32_bf16(af[i], bf[j], acc[i][j], 0, 0, 0);
  }
  #pragma unroll
  for (int j = 0; j < 4; ++j){
    int col = c0 + wcol + j*16 + mrow;
    float bcol = Bb[col];
    #pragma unroll
    for (int i = 0; i < 4; ++i)
      #pragma unroll
      for (int rg = 0; rg < 4; ++rg){
        int rr = row0 + wrow + i*16 + quad*4 + rg;
        if (rr >= n) continue;
        float v = acc[i][j][rg] + bcol;
        if (col < 128){
          kqv[(size_t)rr*384 + col] = f2bf(v);
        } else if (col < 256){
          int jj = col - 128;
          kqv[(size_t)rr*384 + 128 + ((jj >> 1) << 2) + (jj & 1)] = f2bf(v);
        } else if (col < 384){
          int jj = col - 256;
          kqv[(size_t)rr*384 + 128 + ((jj >> 1) << 2) + 2 + (jj & 1)] = f2bf(v);
        } else {
          out[(size_t)rr*H2 + (col - 384)] = v;
        }
      }
  }
}

// ---- one wave per dst node: out[d] += sum_e sigmoid(k[d]+q[s])*v[s] ----
__global__ void k_edge2(const int* __restrict__ off, const int* __restrict__ deg,
                        const int* __restrict__ pk, const unsigned short* __restrict__ kqv,
                        float* __restrict__ out, int n){
  int wid = blockIdx.x*(blockDim.x >> 6) + (threadIdx.x >> 6);
  int lane = threadIdx.x & 63;
  if (wid >= n) return;
  uint32_t ku = ((const uint32_t*)kqv)[(size_t)wid*192 + lane];
  float k0 = bf2f(ku), k1 = bf2f(ku >> 16);
  float a0 = 0.f, a1 = 0.f;
  int o = off[wid], dg = deg[wid];
  for (int j = 0; j < dg; ++j){
    int s = pk[o + j] & 0xFFFFF;
    uint2 qv = *(const uint2*)((const uint32_t*)kqv + (size_t)s*192 + 64 + lane*2);
    float q0 = bf2f(qv.x), q1 = bf2f(qv.x >> 16);
    float v0 = bf2f(qv.y), v1 = bf2f(qv.y >> 16);
    float g0 = 1.f / (1.f + __expf(-(k0 + q0)));
    float g1 = 1.f / (1.f + __expf(-(k1 + q1)));
    a0 += g0*v0; a1 += g1*v1;
  }
  float2* op = (float2*)(out + (size_t)wid*H2);
  float2 cur = op[lane];
  cur.x += a0; cur.y += a1;
  op[lane] = cur;
}

extern "C" void kernel_launch(void* const* d_in, const int* in_sizes, int n_in,
                              void* d_out, int out_size, void* d_ws, size_t ws_size,
                              hipStream_t stream){
  const float* x     = (const float*)d_in[0];
  const int*   eidx  = (const int*)  d_in[1];
  const int*   etype = (const int*)  d_in[3];
  const float* basis = (const float*)d_in[4];
  const float* comp  = (const float*)d_in[5];
  const float* root  = (const float*)d_in[6];
  const float* bias1 = (const float*)d_in[7];
  const float* wk    = (const float*)d_in[8];
  const float* bk    = (const float*)d_in[9];
  const float* wq    = (const float*)d_in[10];
  const float* bq    = (const float*)d_in[11];
  const float* wv    = (const float*)d_in[12];
  const float* bv    = (const float*)d_in[13];
  const float* wsk   = (const float*)d_in[14];
  const float* bs    = (const float*)d_in[15];
  const int n = in_sizes[0] / GD;          // 50000
  const int E = in_sizes[3];               // 600000
  const int npad = (n + 127) & ~127;       // 50048 (multiple of 128)
  const int* esrc = eidx;
  const int* edst = eidx + E;
  float* out = (float*)d_out;

  char* w = (char*)d_ws;
  size_t off = 0;
  unsigned short* xbf  = (unsigned short*)(w + off); off = align256(off + (size_t)n*GD*2);
  unsigned short* Abig = (unsigned short*)(w + off); off = align256(off + (size_t)npad*K1*2);
  unsigned short* B1t  = (unsigned short*)(w + off); off = align256(off + (size_t)H1*K1*2);
  unsigned short* B2t  = (unsigned short*)(w + off); off = align256(off + (size_t)512*H1*2);
  float* Bb            = (float*)(w + off);          off = align256(off + 512*4);
  unsigned short* hbuf = (unsigned short*)(w + off); off = align256(off + (size_t)npad*H1*2);
  unsigned short* kqv  = (unsigned short*)(w + off); off = align256(off + (size_t)n*384*2);
  int* deg             = (int*)(w + off);            off = align256(off + (size_t)npad*4);
  int* offs            = (int*)(w + off);            off = align256(off + (size_t)npad*4);
  int* cursor          = (int*)(w + off);            off = align256(off + (size_t)npad*4);
  int* pk              = (int*)(w + off);            off = align256(off + (size_t)E*4);

  hipMemsetAsync(deg, 0, (size_t)npad*4, stream);

  k_build_B1t<<<(H1*K1 + 255)/256, 256, 0, stream>>>(comp, basis, root, B1t);
  k_build_B2t<<<(512*H1 + 255)/256, 256, 0, stream>>>(wk, wq, wv, wsk, bk, bq, bv, bs, B2t, Bb);
  k_cast_x<<<(n*GD + 255)/256, 256, 0, stream>>>(x, xbf, n*GD);
  k_hist<<<(E + 255)/256, 256, 0, stream>>>(edst, deg, E);
  k_scan<<<1, 1024, 0, stream>>>(deg, offs, cursor, n);
  k_scatter<<<(E + 255)/256, 256, 0, stream>>>(esrc, edst, etype, cursor, pk, E);
  k_edge1<<<(npad + 3)/4, 256, 0, stream>>>(offs, deg, pk, xbf, Abig, n, npad);
  k_gemm1<<<npad/128, 256, 0, stream>>>(Abig, B1t, bias1, hbuf);
  k_gemm2<<<dim3(npad/128, 4), 256, 0, stream>>>(hbuf, B2t, Bb, kqv, out, n);
  k_edge2<<<(n + 3)/4, 256, 0, stream>>>(offs, deg, pk, kqv, out, n);
}

// Round 4
// 430.163 us; speedup vs baseline: 2.7683x; 1.1520x over previous
//
#include <hip/hip_runtime.h>
#include <stdint.h>

#define GD 128
#define H1 128
#define H2 128
#define NBASES 32
#define NREL 8
#define K1 (NREL*GD + GD)   // 1152
#define SCHUNK 8192

typedef __attribute__((ext_vector_type(8))) short bf16x8;
typedef __attribute__((ext_vector_type(4))) float f32x4;

static inline size_t align256(size_t x){ return (x + 255) & ~(size_t)255; }

__device__ __forceinline__ float bf2f(uint32_t u16){
  union { uint32_t u; float f; } c; c.u = (u16 & 0xffffu) << 16; return c.f;
}
__device__ __forceinline__ unsigned short f2bf(float f){
  union { float f; uint32_t u; } c; c.f = f;
  uint32_t u = c.u;
  u += 0x7fffu + ((u >> 16) & 1u);   // RTNE (finite inputs)
  return (unsigned short)(u >> 16);
}

// async global->LDS, 16B per lane; lds dst = wave-uniform base + lane*16
__device__ __forceinline__ void async_copy16(void* lds_dst, const void* gsrc){
  __builtin_amdgcn_global_load_lds(
      (const __attribute__((address_space(1))) uint32_t*)gsrc,
      (__attribute__((address_space(3))) uint32_t*)lds_dst, 16, 0, 0);
}

// ---- B1t[n][k] (bf16, [128][1152]): k<1024 -> W_r rows, else root ----
__global__ void k_build_B1t(const float* __restrict__ comp, const float* __restrict__ basis,
                            const float* __restrict__ root, unsigned short* __restrict__ B1t){
  int idx = blockIdx.x*blockDim.x + threadIdx.x;
  if (idx >= H1*K1) return;
  int nn = idx / K1, kk = idx % K1;
  float v;
  if (kk < NREL*GD){
    int r = kk >> 7, i = kk & 127;
    float acc = 0.f;
    #pragma unroll
    for (int b = 0; b < NBASES; ++b)
      acc += comp[r*NBASES + b] * basis[((size_t)b*GD + i)*H1 + nn];
    v = acc;
  } else {
    v = root[(size_t)(kk - NREL*GD)*H1 + nn];
  }
  B1t[idx] = f2bf(v);
}

// ---- B2t[c][k] (bf16, [512][128]) = [Wk|Wq|Wv|Wskip]^T ; Bb = biases (512 f32) ----
__global__ void k_build_B2t(const float* __restrict__ wk, const float* __restrict__ wq,
                            const float* __restrict__ wv, const float* __restrict__ wsk,
                            const float* __restrict__ bk, const float* __restrict__ bq,
                            const float* __restrict__ bv, const float* __restrict__ bs,
                            unsigned short* __restrict__ B2t, float* __restrict__ Bb){
  int idx = blockIdx.x*blockDim.x + threadIdx.x;
  if (idx < 512*H1){
    int c = idx / H1, k = idx % H1;
    const float* w = (c < 128) ? wk : (c < 256) ? wq : (c < 384) ? wv : wsk;
    B2t[idx] = f2bf(w[(size_t)k*H2 + (c & 127)]);
  }
  if (idx < 512){
    const float* b = (idx < 128) ? bk : (idx < 256) ? bq : (idx < 384) ? bv : bs;
    Bb[idx] = b[idx & 127];
  }
}

__global__ void k_cast_x(const float* __restrict__ x, unsigned short* __restrict__ xbf, int cnt){
  int idx = blockIdx.x*blockDim.x + threadIdx.x;
  if (idx < cnt) xbf[idx] = f2bf(x[idx]);
}

__global__ void k_hist(const int* __restrict__ dst, int* __restrict__ deg, int E){
  int e = blockIdx.x*blockDim.x + threadIdx.x;
  if (e < E) atomicAdd(&deg[dst[e]], 1);
}

// ---- parallel scan, stage A: per-block (8192) local exclusive scan + block total ----
__global__ void k_scanA(const int* __restrict__ deg, int* __restrict__ off,
                        int* __restrict__ btot, int n){
  __shared__ int wsum[16];
  int t = threadIdx.x, lane = t & 63, w = t >> 6;
  int i0 = blockIdx.x*SCHUNK + t*8;
  int v[8];
  if (i0 + 7 < n){
    int4 va = *(const int4*)(deg + i0);
    int4 vb = *(const int4*)(deg + i0 + 4);
    v[0]=va.x; v[1]=va.y; v[2]=va.z; v[3]=va.w;
    v[4]=vb.x; v[5]=vb.y; v[6]=vb.z; v[7]=vb.w;
  } else {
    #pragma unroll
    for (int u = 0; u < 8; ++u) v[u] = (i0+u < n) ? deg[i0+u] : 0;
  }
  int s[8]; s[0] = v[0];
  #pragma unroll
  for (int u = 1; u < 8; ++u) s[u] = s[u-1] + v[u];
  int x = s[7];
  #pragma unroll
  for (int d = 1; d < 64; d <<= 1){
    int u = __shfl_up(x, d, 64);
    if (lane >= d) x += u;
  }
  if (lane == 63) wsum[w] = x;
  __syncthreads();
  if (t < 16){
    int y = wsum[t];
    #pragma unroll
    for (int d = 1; d < 16; d <<= 1){
      int u = __shfl_up(y, d, 16);
      if (t >= d) y += u;
    }
    wsum[t] = y;
  }
  __syncthreads();
  int woff = (w > 0) ? wsum[w-1] : 0;
  int excl = woff + x - s[7];
  #pragma unroll
  for (int u = 0; u < 8; ++u)
    if (i0+u < n) off[i0+u] = excl + s[u] - v[u];
  if (t == 0) btot[blockIdx.x] = wsum[15];
}

// ---- scan stage B: add prefix of block totals; emit cursor copy ----
__global__ void k_scanB(const int* __restrict__ btot, int* __restrict__ off,
                        int* __restrict__ cursor, int n){
  int t = threadIdx.x, bid = blockIdx.x;
  int add = 0;
  for (int j = 0; j < bid; ++j) add += btot[j];
  int i0 = bid*SCHUNK + t*8;
  #pragma unroll
  for (int u = 0; u < 8; ++u){
    int i = i0 + u;
    if (i < n){ int val = off[i] + add; off[i] = val; cursor[i] = val; }
  }
}

// pk[pos] = src | (typ<<20), dst-sorted via cursor
__global__ void k_scatter(const int* __restrict__ src, const int* __restrict__ dst,
                          const int* __restrict__ typ, int* __restrict__ cursor,
                          int* __restrict__ pk, int E){
  int e = blockIdx.x*blockDim.x + threadIdx.x;
  if (e >= E) return;
  int pos = atomicAdd(&cursor[dst[e]], 1);
  pk[pos] = src[e] | (typ[e] << 20);
}

// ---- one wave per dst node: per-relation mean of x[src] -> Abig row (bf16) ----
// edge list broadcast via readlane (r is wave-uniform -> scalar switch), gather
// software-pipelined one edge ahead.
__global__ void k_edge1(const int* __restrict__ off, const int* __restrict__ deg,
                        const int* __restrict__ pk, const unsigned short* __restrict__ xbf,
                        unsigned short* __restrict__ Abig, int n, int npad){
  int wid = blockIdx.x*(blockDim.x >> 6) + (threadIdx.x >> 6);
  int lane = threadIdx.x & 63;
  if (wid >= npad) return;
  uint32_t* Arow = (uint32_t*)(Abig + (size_t)wid*K1);
  if (wid >= n){
    #pragma unroll
    for (int r = 0; r < 9; ++r) Arow[r*64 + lane] = 0u;
    return;
  }
  const uint32_t* x32 = (const uint32_t*)xbf;
  float a0[8], a1[8]; int cr[8];
  #pragma unroll
  for (int r = 0; r < 8; ++r){ a0[r] = 0.f; a1[r] = 0.f; cr[r] = 0; }
  int o = off[wid], dg = deg[wid];
  for (int jb = 0; jb < dg; jb += 64){
    int pj = (jb + lane < dg) ? pk[o + jb + lane] : 0;
    int m = dg - jb; if (m > 64) m = 64;
    int p = __builtin_amdgcn_readlane(pj, 0);
    uint32_t xv = x32[(size_t)(p & 0xFFFFF)*64 + lane];
    for (int jj = 0; jj < m; ++jj){
      int r = (p >> 20) & 7;
      uint32_t xc = xv;
      if (jj + 1 < m){
        p = __builtin_amdgcn_readlane(pj, jj + 1);
        xv = x32[(size_t)(p & 0xFFFFF)*64 + lane];
      }
      float x0 = bf2f(xc), x1 = bf2f(xc >> 16);
      switch (r){
        case 0: a0[0]+=x0; a1[0]+=x1; cr[0]++; break;
        case 1: a0[1]+=x0; a1[1]+=x1; cr[1]++; break;
        case 2: a0[2]+=x0; a1[2]+=x1; cr[2]++; break;
        case 3: a0[3]+=x0; a1[3]+=x1; cr[3]++; break;
        case 4: a0[4]+=x0; a1[4]+=x1; cr[4]++; break;
        case 5: a0[5]+=x0; a1[5]+=x1; cr[5]++; break;
        case 6: a0[6]+=x0; a1[6]+=x1; cr[6]++; break;
        default: a0[7]+=x0; a1[7]+=x1; cr[7]++; break;
      }
    }
  }
  #pragma unroll
  for (int rr = 0; rr < 8; ++rr){
    float inv = 1.f / (float)(cr[rr] > 0 ? cr[rr] : 1);
    Arow[rr*64 + lane] = (uint32_t)f2bf(a0[rr]*inv) | ((uint32_t)f2bf(a1[rr]*inv) << 16);
  }
  Arow[512 + lane] = x32[(size_t)wid*64 + lane];
}

// =================== m97-style tiled MFMA GEMMs ===================
__launch_bounds__(256)
__global__ void k_gemm1(const unsigned short* __restrict__ A, const unsigned short* __restrict__ Bt,
                        const float* __restrict__ bias, unsigned short* __restrict__ h){
  __shared__ char lds[16384];
  int t = threadIdx.x, lane = t & 63, wave = t >> 6;
  int row0 = blockIdx.x * 128;
  int mrow = lane & 15, quad = lane >> 4;
  int wrow = (wave & 1) * 64, wcol = (wave >> 1) * 64;
  int s = (mrow >> 1) & 3;

  const unsigned short* Asrc = A + (size_t)(row0 + (t >> 2))*K1 + (((t & 3) ^ ((t >> 3) & 3)) << 3);
  const unsigned short* Bsrc = Bt + (size_t)(t >> 2)*K1 + (((t & 3) ^ ((t >> 3) & 3)) << 3);
  char* ldsw = lds + wave*1024;

  int aoff = (wrow + mrow)*64 + ((quad ^ s) << 4);
  int boff = 8192 + (wcol + mrow)*64 + ((quad ^ s) << 4);

  f32x4 acc[4][4];
  #pragma unroll
  for (int i = 0; i < 4; ++i)
    #pragma unroll
    for (int j = 0; j < 4; ++j) acc[i][j] = (f32x4){0.f,0.f,0.f,0.f};

  for (int kt = 0; kt < K1; kt += 32){
    __syncthreads();
    async_copy16(ldsw,                 Asrc + kt);
    async_copy16(ldsw + 4096,          Asrc + (size_t)64*K1 + kt);
    async_copy16(ldsw + 8192,          Bsrc + kt);
    async_copy16(ldsw + 12288,         Bsrc + (size_t)64*K1 + kt);
    __syncthreads();
    bf16x8 af[4], bf[4];
    #pragma unroll
    for (int i = 0; i < 4; ++i) af[i] = *(const bf16x8*)(lds + aoff + i*1024);
    #pragma unroll
    for (int j = 0; j < 4; ++j) bf[j] = *(const bf16x8*)(lds + boff + j*1024);
    #pragma unroll
    for (int i = 0; i < 4; ++i)
      #pragma unroll
      for (int j = 0; j < 4; ++j)
        acc[i][j] = __builtin_amdgcn_mfma_f32_16x16x32_bf16(af[i], bf[j], acc[i][j], 0, 0, 0);
  }
  #pragma unroll
  for (int j = 0; j < 4; ++j){
    int col = wcol + j*16 + mrow;
    float bcol = bias[col];
    #pragma unroll
    for (int i = 0; i < 4; ++i)
      #pragma unroll
      for (int rg = 0; rg < 4; ++rg){
        int row = wrow + i*16 + quad*4 + rg;
        h[(size_t)(row0 + row)*H1 + col] = f2bf(acc[i][j][rg] + bcol);
      }
  }
}

__launch_bounds__(256)
__global__ void k_gemm2(const unsigned short* __restrict__ A, const unsigned short* __restrict__ Bt,
                        const float* __restrict__ Bb, unsigned short* __restrict__ kqv,
                        float* __restrict__ out, int n){
  __shared__ char lds[16384];
  int t = threadIdx.x, lane = t & 63, wave = t >> 6;
  int row0 = blockIdx.x * 128;
  int c0 = blockIdx.y * 128;
  int mrow = lane & 15, quad = lane >> 4;
  int wrow = (wave & 1) * 64, wcol = (wave >> 1) * 64;
  int s = (mrow >> 1) & 3;

  const unsigned short* Asrc = A + (size_t)(row0 + (t >> 2))*H1 + (((t & 3) ^ ((t >> 3) & 3)) << 3);
  const unsigned short* Bsrc = Bt + (size_t)(c0 + (t >> 2))*H1 + (((t & 3) ^ ((t >> 3) & 3)) << 3);
  char* ldsw = lds + wave*1024;

  int aoff = (wrow + mrow)*64 + ((quad ^ s) << 4);
  int boff = 8192 + (wcol + mrow)*64 + ((quad ^ s) << 4);

  f32x4 acc[4][4];
  #pragma unroll
  for (int i = 0; i < 4; ++i)
    #pragma unroll
    for (int j = 0; j < 4; ++j) acc[i][j] = (f32x4){0.f,0.f,0.f,0.f};

  #pragma unroll
  for (int kt = 0; kt < H1; kt += 32){
    __syncthreads();
    async_copy16(ldsw,         Asrc + kt);
    async_copy16(ldsw + 4096,  Asrc + (size_t)64*H1 + kt);
    async_copy16(ldsw + 8192,  Bsrc + kt);
    async_copy16(ldsw + 12288, Bsrc + (size_t)64*H1 + kt);
    __syncthreads();
    bf16x8 af[4], bf[4];
    #pragma unroll
    for (int i = 0; i < 4; ++i) af[i] = *(const bf16x8*)(lds + aoff + i*1024);
    #pragma unroll
    for (int j = 0; j < 4; ++j) bf[j] = *(const bf16x8*)(lds + boff + j*1024);
    #pragma unroll
    for (int i = 0; i < 4; ++i)
      #pragma unroll
      for (int j = 0; j < 4; ++j)
        acc[i][j] = __builtin_amdgcn_mfma_f32_16x16x32_bf16(af[i], bf[j], acc[i][j], 0, 0, 0);
  }
  #pragma unroll
  for (int j = 0; j < 4; ++j){
    int col = c0 + wcol + j*16 + mrow;
    float bcol = Bb[col];
    #pragma unroll
    for (int i = 0; i < 4; ++i)
      #pragma unroll
      for (int rg = 0; rg < 4; ++rg){
        int rr = row0 + wrow + i*16 + quad*4 + rg;
        if (rr >= n) continue;
        float v = acc[i][j][rg] + bcol;
        if (col < 128){
          kqv[(size_t)rr*384 + col] = f2bf(v);
        } else if (col < 256){
          int jj = col - 128;
          kqv[(size_t)rr*384 + 128 + ((jj >> 1) << 2) + (jj & 1)] = f2bf(v);
        } else if (col < 384){
          int jj = col - 256;
          kqv[(size_t)rr*384 + 128 + ((jj >> 1) << 2) + 2 + (jj & 1)] = f2bf(v);
        } else {
          out[(size_t)rr*H2 + (col - 384)] = v;
        }
      }
  }
}

// ---- one wave per dst node: out[d] += sum_e sigmoid(k[d]+q[s])*v[s] ----
__global__ void k_edge2(const int* __restrict__ off, const int* __restrict__ deg,
                        const int* __restrict__ pk, const unsigned short* __restrict__ kqv,
                        float* __restrict__ out, int n){
  int wid = blockIdx.x*(blockDim.x >> 6) + (threadIdx.x >> 6);
  int lane = threadIdx.x & 63;
  if (wid >= n) return;
  const uint32_t* kv32 = (const uint32_t*)kqv;
  uint32_t ku = kv32[(size_t)wid*192 + lane];
  float k0 = bf2f(ku), k1 = bf2f(ku >> 16);
  float a0 = 0.f, a1 = 0.f;
  int o = off[wid], dg = deg[wid];
  for (int jb = 0; jb < dg; jb += 64){
    int pj = (jb + lane < dg) ? pk[o + jb + lane] : 0;
    int m = dg - jb; if (m > 64) m = 64;
    int p = __builtin_amdgcn_readlane(pj, 0);
    uint2 qv = *(const uint2*)(kv32 + (size_t)(p & 0xFFFFF)*192 + 64 + lane*2);
    for (int jj = 0; jj < m; ++jj){
      uint2 qc = qv;
      if (jj + 1 < m){
        p = __builtin_amdgcn_readlane(pj, jj + 1);
        qv = *(const uint2*)(kv32 + (size_t)(p & 0xFFFFF)*192 + 64 + lane*2);
      }
      float q0 = bf2f(qc.x), q1 = bf2f(qc.x >> 16);
      float v0 = bf2f(qc.y), v1 = bf2f(qc.y >> 16);
      float g0 = 1.f / (1.f + __expf(-(k0 + q0)));
      float g1 = 1.f / (1.f + __expf(-(k1 + q1)));
      a0 += g0*v0; a1 += g1*v1;
    }
  }
  float2* op = (float2*)(out + (size_t)wid*H2);
  float2 cur = op[lane];
  cur.x += a0; cur.y += a1;
  op[lane] = cur;
}

extern "C" void kernel_launch(void* const* d_in, const int* in_sizes, int n_in,
                              void* d_out, int out_size, void* d_ws, size_t ws_size,
                              hipStream_t stream){
  const float* x     = (const float*)d_in[0];
  const int*   eidx  = (const int*)  d_in[1];
  const int*   etype = (const int*)  d_in[3];
  const float* basis = (const float*)d_in[4];
  const float* comp  = (const float*)d_in[5];
  const float* root  = (const float*)d_in[6];
  const float* bias1 = (const float*)d_in[7];
  const float* wk    = (const float*)d_in[8];
  const float* bk    = (const float*)d_in[9];
  const float* wq    = (const float*)d_in[10];
  const float* bq    = (const float*)d_in[11];
  const float* wv    = (const float*)d_in[12];
  const float* bv    = (const float*)d_in[13];
  const float* wsk   = (const float*)d_in[14];
  const float* bs    = (const float*)d_in[15];
  const int n = in_sizes[0] / GD;          // 50000
  const int E = in_sizes[3];               // 600000
  const int npad = (n + 127) & ~127;       // 50048
  const int* esrc = eidx;
  const int* edst = eidx + E;
  float* out = (float*)d_out;

  char* w = (char*)d_ws;
  size_t off = 0;
  unsigned short* xbf  = (unsigned short*)(w + off); off = align256(off + (size_t)n*GD*2);
  unsigned short* Abig = (unsigned short*)(w + off); off = align256(off + (size_t)npad*K1*2);
  unsigned short* B1t  = (unsigned short*)(w + off); off = align256(off + (size_t)H1*K1*2);
  unsigned short* B2t  = (unsigned short*)(w + off); off = align256(off + (size_t)512*H1*2);
  float* Bb            = (float*)(w + off);          off = align256(off + 512*4);
  unsigned short* hbuf = (unsigned short*)(w + off); off = align256(off + (size_t)npad*H1*2);
  unsigned short* kqv  = (unsigned short*)(w + off); off = align256(off + (size_t)n*384*2);
  int* deg             = (int*)(w + off);            off = align256(off + (size_t)npad*4);
  int* offs            = (int*)(w + off);            off = align256(off + (size_t)npad*4);
  int* cursor          = (int*)(w + off);            off = align256(off + (size_t)npad*4);
  int* btot            = (int*)(w + off);            off = align256(off + 64*4);
  int* pk              = (int*)(w + off);            off = align256(off + (size_t)E*4);

  const int nblk = (n + SCHUNK - 1) / SCHUNK;   // 7

  hipMemsetAsync(deg, 0, (size_t)npad*4, stream);

  k_build_B1t<<<(H1*K1 + 255)/256, 256, 0, stream>>>(comp, basis, root, B1t);
  k_build_B2t<<<(512*H1 + 255)/256, 256, 0, stream>>>(wk, wq, wv, wsk, bk, bq, bv, bs, B2t, Bb);
  k_cast_x<<<(n*GD + 255)/256, 256, 0, stream>>>(x, xbf, n*GD);
  k_hist<<<(E + 255)/256, 256, 0, stream>>>(edst, deg, E);
  k_scanA<<<nblk, 1024, 0, stream>>>(deg, offs, btot, n);
  k_scanB<<<nblk, 1024, 0, stream>>>(btot, offs, cursor, n);
  k_scatter<<<(E + 255)/256, 256, 0, stream>>>(esrc, edst, etype, cursor, pk, E);
  k_edge1<<<(npad + 3)/4, 256, 0, stream>>>(offs, deg, pk, xbf, Abig, n, npad);
  k_gemm1<<<npad/128, 256, 0, stream>>>(Abig, B1t, bias1, hbuf);
  k_gemm2<<<dim3(npad/128, 4), 256, 0, stream>>>(hbuf, B2t, Bb, kqv, out, n);
  k_edge2<<<(n + 3)/4, 256, 0, stream>>>(offs, deg, pk, kqv, out, n);
}